// Round 11
// baseline (58.294 us; speedup 1.0000x reference)
//
#include <hip/hip_runtime.h>
#include <math.h>

#define HW     262144   // 512*512
#define WIDTH  512
#define BB     4
#define NN     32
#define KK     256
#define PP     8192
#define EPSF   1e-4f
#define ONE_M_EPS (1.0f - 1e-4f)

// ================= shared helpers =================
__device__ __forceinline__ float ftanh(float x) {
    float e = __expf(2.0f * x);
    return 1.0f - 2.0f / (e + 1.0f);
}

__device__ __forceinline__ float wave_reduce(float v) {
    #pragma unroll
    for (int off = 1; off < 64; off <<= 1) v += __shfl_xor(v, off, 64);
    return v;
}

__device__ __forceinline__ float block_reduce(float v, float* sbuf) {
    v = wave_reduce(v);
    int lane = threadIdx.x & 63, wid = threadIdx.x >> 6;
    __syncthreads();
    if (lane == 0) sbuf[wid] = v;
    __syncthreads();
    float r = 0.f;
    if (threadIdx.x == 0) {
        for (int i = 0; i < 4; ++i) r += sbuf[i];
    }
    return r;
}

// ---- small-family parts (base-pointer parametrized, shared by both paths) ----
__device__ __forceinline__ void focal_part(int idx, const float* __restrict__ cls_out,
                                           const float* __restrict__ cls_mask,
                                           const float* __restrict__ kp_out,
                                           const float* __restrict__ kp_mask,
                                           float* __restrict__ dst, float* sbuf) {
    int t = idx >> 8, blk = idx & 255;
    const float4* po = (const float4*)(t == 0 ? cls_out : kp_out);
    const float4* pm = (const float4*)(t == 0 ? cls_mask : kp_mask);
    float sum = 0.f, cnt = 0.f;
    #pragma unroll
    for (int it = 0; it < 4; ++it) {
        int i = blk * 256 + threadIdx.x + it * 65536;
        float4 xo = po[i], xm = pm[i];
        #pragma unroll
        for (int j = 0; j < 4; ++j) {
            float x = (&xo.x)[j], gt = (&xm.x)[j];
            float p = 1.0f / (1.0f + __expf(-x));
            p = fminf(fmaxf(p, EPSF), ONE_M_EPS);
            float omp = 1.0f - p;
            float pos_t = __logf(p) * omp * omp;
            float og = 1.0f - gt;
            float negw = og * og; negw *= negw;
            float neg_t = __logf(omp) * p * p * negw;
            bool ispos = (gt == 1.0f);
            sum += ispos ? pos_t : neg_t;
            cnt += ispos ? 1.0f : 0.0f;
        }
    }
    float r0 = block_reduce(sum, sbuf);
    float r1 = block_reduce(cnt, sbuf);
    if (threadIdx.x == 0) { dst[idx * 2] = r0; dst[idx * 2 + 1] = r1; }
}

__device__ __forceinline__ void wh_part(int blk, const float* __restrict__ o,
                                        const float* __restrict__ tg,
                                        const float* __restrict__ m,
                                        float* __restrict__ dst, float* sbuf) {
    const float4* po  = (const float4*)o;
    const float4* pt  = (const float4*)tg;
    const float4* pmk = (const float4*)m;
    float sl = 0.f, ms = 0.f;
    #pragma unroll
    for (int it = 0; it < 8; ++it) {
        int i = blk * 256 + threadIdx.x + it * 65536;
        float4 a = po[i], b = pt[i], c = pmk[i];
        #pragma unroll
        for (int j = 0; j < 4; ++j) {
            float mm = (&c.x)[j];
            float d  = (&a.x)[j] * mm - (&b.x)[j] * mm;
            float ad = fabsf(d);
            sl += (ad < 1.0f) ? 0.5f * d * d : (ad - 0.5f);
            ms += mm;
        }
    }
    float r0 = block_reduce(sl, sbuf);
    float r1 = block_reduce(ms, sbuf);
    if (threadIdx.x == 0) { dst[blk * 2] = r0; dst[blk * 2 + 1] = r1; }
}

__device__ __forceinline__ void tan_part(int idx, const float* __restrict__ tan_out,
                                         const float* __restrict__ normals,
                                         const int* __restrict__ pts,
                                         float* __restrict__ dst, float* sbuf) {
    int b = idx >> 3, seg = idx & 7;
    float s = 0.f;
    for (int p = seg * 1024 + threadIdx.x; p < seg * 1024 + 1024; p += 256) {
        int base = (b * PP + p) * 2;
        int py = pts[base], px = pts[base + 1];
        int pix = py * WIDTH + px;
        float t0 = tan_out[b * 2 * HW + pix];
        float t1 = tan_out[b * 2 * HW + HW + pix];
        float inv = 1.0f / fmaxf(sqrtf(t0 * t0 + t1 * t1), EPSF);
        float n0 = normals[base], n1 = normals[base + 1];
        s += 1.0f - (n0 * t0 + n1 * t1) * inv;
    }
    float r = block_reduce(s, sbuf);
    if (threadIdx.x == 0) dst[idx] = r;
}

__device__ __forceinline__ void var_part(int idx, const float* __restrict__ ae,
                                         const int* __restrict__ centers,
                                         const int* __restrict__ kps,
                                         float* __restrict__ dst, float* smem) {
    int n = idx & 31, b = idx >> 5;
    float* cy = smem, *cx = smem + 32, *sbuf = smem + 64;
    if (threadIdx.x < NN) {
        int cb = (b * NN + threadIdx.x) * 2;
        cy[threadIdx.x] = centers[cb]     * (1.0f / 512.0f);
        cx[threadIdx.x] = centers[cb + 1] * (1.0f / 512.0f);
    }
    __syncthreads();
    int k = threadIdx.x;
    int kb = ((b * NN + n) * KK + k) * 2;
    int ky = kps[kb], kx = kps[kb + 1];
    int pix = ky * WIDTH + kx;
    const float* aeb = ae + (size_t)b * 4 * HW;
    float se0 = ftanh(aeb[pix])      + ky * (1.0f / 512.0f);
    float se1 = ftanh(aeb[HW + pix]) + kx * (1.0f / 512.0f);
    float sg0 = __expf(aeb[2 * HW + pix]);
    float sg1 = __expf(aeb[3 * HW + pix]);
    float own = 0.f, mx = -1e30f;
    #pragma unroll
    for (int m = 0; m < NN; ++m) {
        float d0 = se0 - cy[m], d1 = se1 - cx[m];
        float dist = __expf(-(d0 * d0 * sg0 + d1 * d1 * sg1));
        mx = fmaxf(mx, dist);
        if (m == n) own = dist;
    }
    float r = block_reduce(fabsf(own - mx), sbuf);
    if (threadIdx.x == 0) dst[b * NN + n] = r;
}

// ================= BIG path: precompute se/sg -> ws, lean sweep =================
// ws float layout: [0, 4194304) sesg as float4[(b*4+p)*65536 + vo]
#define B_SESG_F 4194304
#define B_INST   (B_SESG_F)            // [1024][8]
#define B_FOCAL  (B_INST + 8192)       // [2][256][2]
#define B_WH     (B_FOCAL + 1024)      // [256][2]
#define B_TAN    (B_WH + 512)          // [32]
#define B_VAR    (B_TAN + 32)          // [128]
#define B_END    (B_VAR + 128)         // 4204192 floats

// 1024 blocks: thread computes one f4 of se0/se1/sg0/sg1 and stores 4 float4s.
__global__ void __launch_bounds__(256)
k_pre(const float* __restrict__ ae, float* __restrict__ ws) {
    int v4 = blockIdx.x * 256 + threadIdx.x;   // 0..262143
    int b = v4 >> 16, vo = v4 & 65535;
    const float4* aeb = (const float4*)ae + (size_t)b * 4 * 65536;
    float4 a0 = aeb[vo];
    float4 a1 = aeb[65536 + vo];
    float4 a2 = aeb[131072 + vo];
    float4 a3 = aeb[196608 + vo];
    int pix0 = vo * 4;
    float fy  = (float)(pix0 >> 9)  * (1.0f / 512.0f);
    float fx0 = (float)(pix0 & 511) * (1.0f / 512.0f);
    float4 s0, s1, s2, s3;
    #pragma unroll
    for (int j = 0; j < 4; ++j) {
        (&s0.x)[j] = ftanh((&a0.x)[j]) + fy;
        (&s1.x)[j] = ftanh((&a1.x)[j]) + fx0 + (float)j * (1.0f / 512.0f);
        (&s2.x)[j] = __expf((&a2.x)[j]);
        (&s3.x)[j] = __expf((&a3.x)[j]);
    }
    float4* sg = (float4*)ws;
    sg[((size_t)(b * 4 + 0) << 16) + vo] = s0;
    sg[((size_t)(b * 4 + 1) << 16) + vo] = s1;
    sg[((size_t)(b * 4 + 2) << 16) + vo] = s2;
    sg[((size_t)(b * 4 + 3) << 16) + vo] = s3;
}

// sweep: idx = b*256 + grp*32 + seg (grp: 8 groups of 4 inst; seg: 32KB segment)
__device__ __forceinline__ void sweep_part(int idx, const float* __restrict__ masks,
                                           const int* __restrict__ centers,
                                           const float* __restrict__ ws_ro,
                                           float* __restrict__ wsi,
                                           float* __restrict__ s_part) { // [4][8]
    const int tid = threadIdx.x, lane = tid & 63, w = tid >> 6;
    const int b = idx >> 8, grp = (idx >> 5) & 7, seg = idx & 31;
    const float4* sesgb = (const float4*)ws_ro + ((size_t)(b * 4) << 16);
    const float4* mbase = (const float4*)masks + ((size_t)(b * NN + grp * 4) << 16);
    const int segf4 = seg * 2048;     // 2048 f4 = 32KB
    const int* cb = centers + (b * NN + grp * 4) * 2;

    #pragma unroll 1
    for (int il = 0; il < 4; ++il) {
        float cy = (float)cb[il * 2]     * (1.0f / 512.0f);   // wave-uniform
        float cx = (float)cb[il * 2 + 1] * (1.0f / 512.0f);
        const float4* mp = mbase + ((size_t)il << 16) + segf4;
        float sum = 0.f, cnt = 0.f;
        float4 mk = mp[tid];
        #pragma unroll
        for (int it = 0; it < 8; ++it) {
            float4 mk_n;
            if (it < 7) mk_n = mp[(it + 1) * 256 + tid];     // sequential prefetch
            int v = segf4 + it * 256 + tid;
            float4 s0 = sesgb[v];
            float4 s1 = sesgb[65536 + v];
            float4 s2 = sesgb[131072 + v];
            float4 s3 = sesgb[196608 + v];
            #pragma unroll
            for (int j = 0; j < 4; ++j) {
                float m  = (&mk.x)[j];                 // exactly 0.0 or 1.0
                float dy = (&s0.x)[j] - cy, dx = (&s1.x)[j] - cx;
                float s  = fmaf(dx * dx, (&s3.x)[j], dy * dy * (&s2.x)[j]);
                float e  = __expf(-s);
                float pc = fminf(fmaxf(e, EPSF), ONE_M_EPS);
                float omp = 1.0f - pc;
                // pos: log(pc)*omp^2 ; neg: log(omp)*pc^2 (neg_w==1, binary mask)
                float A = (m != 0.f) ? pc : omp;
                float B = 1.0f - A;
                sum = fmaf(__logf(A), B * B, sum);
                cnt += m;
            }
            mk = mk_n;
        }
        float r0 = wave_reduce(sum);
        float r1 = wave_reduce(cnt);
        if (lane == 0) {
            s_part[w * 8 + il * 2 + 0] = r0;
            s_part[w * 8 + il * 2 + 1] = r1;
        }
    }
    __syncthreads();
    if (tid < 8) {
        float s = s_part[tid] + s_part[8 + tid] + s_part[16 + tid] + s_part[24 + tid];
        wsi[idx * 8 + tid] = s;
    }
}

#define BGS_INST  1024
#define BGS_WH    256
#define BGS_FOCAL 512
#define BGS_TAN   32
#define BGS_VAR   128
#define BGO_WH    BGS_INST
#define BGO_FOCAL (BGO_WH + BGS_WH)
#define BGO_TAN   (BGO_FOCAL + BGS_FOCAL)
#define BGO_VAR   (BGO_TAN + BGS_TAN)
#define BGS_TOTAL (BGO_VAR + BGS_VAR)   // 1952

__global__ void __launch_bounds__(256)
k_sweep(const float* __restrict__ cls_out, const float* __restrict__ wh_out,
        const float* __restrict__ kp_out,  const float* __restrict__ ae_out,
        const float* __restrict__ tan_out, const float* __restrict__ cls_mask,
        const float* __restrict__ wh_target, const float* __restrict__ wh_mask,
        const float* __restrict__ kp_mask, const float* __restrict__ ae_masks,
        const float* __restrict__ tan_normals,
        const int* __restrict__ centers, const int* __restrict__ kps,
        const int* __restrict__ tan_points, float* __restrict__ ws) {
    __shared__ float smem[256];
    int bid = blockIdx.x;
    if (bid < BGS_INST) {
        sweep_part(bid, ae_masks, centers, ws, ws + B_INST, smem);
    } else if (bid < BGO_FOCAL) {
        wh_part(bid - BGO_WH, wh_out, wh_target, wh_mask, ws + B_WH, smem);
    } else if (bid < BGO_TAN) {
        focal_part(bid - BGO_FOCAL, cls_out, cls_mask, kp_out, kp_mask, ws + B_FOCAL, smem);
    } else if (bid < BGO_VAR) {
        tan_part(bid - BGO_TAN, tan_out, tan_normals, tan_points, ws + B_TAN, smem);
    } else {
        var_part(bid - BGO_VAR, ae_out, centers, kps, ws + B_VAR, smem);
    }
}

__global__ void __launch_bounds__(256)
k_final_big(const float* __restrict__ ws, float* __restrict__ out) {
    __shared__ float sbuf[4];
    int tid = threadIdx.x;
    float ae_v = 0.f;
    if (tid < 128) {   // tid = b*32 + n ; n = grp*4 + i
        int b = tid >> 5, n = tid & 31, grp = n >> 2, i = n & 3;
        const float* base = ws + B_INST + (size_t)((b * 8 + grp) * 32) * 8 + i * 2;
        float sum = 0.f, cnt = 0.f;
        #pragma unroll 8
        for (int seg = 0; seg < 32; ++seg) { sum += base[seg * 8]; cnt += base[seg * 8 + 1]; }
        ae_v = -sum / fmaxf(cnt, 1.0f) + ws[B_VAR + tid];
    }
    float ae_sum = block_reduce(ae_v, sbuf);

    float cls_sum = block_reduce(ws[B_FOCAL + tid * 2], sbuf);
    float cls_cnt = block_reduce(ws[B_FOCAL + tid * 2 + 1], sbuf);
    float kp_sum  = block_reduce(ws[B_FOCAL + 512 + tid * 2], sbuf);
    float kp_cnt  = block_reduce(ws[B_FOCAL + 512 + tid * 2 + 1], sbuf);
    float wh_sl   = block_reduce(ws[B_WH + tid * 2], sbuf);
    float wh_ms   = block_reduce(ws[B_WH + tid * 2 + 1], sbuf);
    float tan_sum = block_reduce(tid < 32 ? ws[B_TAN + tid] : 0.f, sbuf);

    if (tid == 0) {
        float l_cls = -cls_sum / fmaxf(cls_cnt, 1.0f);
        float l_kp  = -kp_sum  / fmaxf(kp_cnt,  1.0f);
        float l_wh  = 0.1f * wh_sl / (wh_ms + 1e-4f);
        float l_ae  = ae_sum / (float)(NN * BB);
        float l_tan = tan_sum / (float)(PP * BB);
        out[0] = l_cls + l_wh + l_kp + l_ae + l_tan;
    }
}

// ================= SMALL path: R10 verbatim (fallback if ws too small) =================
#define S_NBLK_INST  512
#define S_NBLK_WH    256
#define S_NBLK_FOCAL 512
#define S_NBLK_TAN   32
#define S_NBLK_VAR   128
#define S_OFF_WH     S_NBLK_INST
#define S_OFF_FOCAL  (S_OFF_WH + S_NBLK_WH)
#define S_OFF_TAN    (S_OFF_FOCAL + S_NBLK_FOCAL)
#define S_OFF_VAR    (S_OFF_TAN + S_NBLK_TAN)
#define S_NBLK_TOTAL (S_OFF_VAR + S_NBLK_VAR)
#define S_INST  0
#define S_FOCAL 8192
#define S_WH    9216
#define S_TAN   9728
#define S_VAR   9760

__device__ __forceinline__ void inst_r10(int idx, const float* __restrict__ ae,
                                         const float* __restrict__ masks,
                                         const int* __restrict__ centers,
                                         float* __restrict__ dst,
                                         float* __restrict__ s_part) {
    const int tid = threadIdx.x, lane = tid & 63, w = tid >> 6;
    const int b = idx >> 7, grp = (idx >> 5) & 3, seg = idx & 31;
    const float4* aeb   = (const float4*)ae + (size_t)b * 4 * 65536;
    const float4* mbase = (const float4*)masks + ((size_t)(b * NN + grp * 8) << 16);
    const int segf4 = seg * 2048;
    const int* cb = centers + (b * NN + grp * 8) * 2;

    #pragma unroll 1
    for (int il = 0; il < 8; ++il) {
        float cy = (float)cb[il * 2]     * (1.0f / 512.0f);
        float cx = (float)cb[il * 2 + 1] * (1.0f / 512.0f);
        const float4* mp = mbase + ((size_t)il << 16) + segf4;
        float sum = 0.f, cnt = 0.f;
        float4 mk = mp[tid];
        #pragma unroll
        for (int it = 0; it < 8; ++it) {
            float4 mk_n;
            if (it < 7) mk_n = mp[(it + 1) * 256 + tid];
            int v = segf4 + it * 256 + tid;
            float4 a0 = aeb[v];
            float4 a1 = aeb[65536 + v];
            float4 a2 = aeb[131072 + v];
            float4 a3 = aeb[196608 + v];
            int pix0 = v * 4;
            float fy  = (float)(pix0 >> 9)  * (1.0f / 512.0f);
            float fx0 = (float)(pix0 & 511) * (1.0f / 512.0f);
            #pragma unroll
            for (int j = 0; j < 4; ++j) {
                float se0 = ftanh((&a0.x)[j]) + fy;
                float se1 = ftanh((&a1.x)[j]) + fx0 + (float)j * (1.0f / 512.0f);
                float sg0 = __expf((&a2.x)[j]);
                float sg1 = __expf((&a3.x)[j]);
                float m  = (&mk.x)[j];
                float dy = se0 - cy, dx = se1 - cx;
                float s  = fmaf(dx * dx, sg1, dy * dy * sg0);
                float e  = __expf(-s);
                float pc = fminf(fmaxf(e, EPSF), ONE_M_EPS);
                float omp = 1.0f - pc;
                float A = (m != 0.f) ? pc : omp;
                float B = 1.0f - A;
                sum = fmaf(__logf(A), B * B, sum);
                cnt += m;
            }
            mk = mk_n;
        }
        float r0 = wave_reduce(sum);
        float r1 = wave_reduce(cnt);
        if (lane == 0) {
            s_part[w * 16 + il * 2 + 0] = r0;
            s_part[w * 16 + il * 2 + 1] = r1;
        }
    }
    __syncthreads();
    if (tid < 16) {
        float s = s_part[tid] + s_part[16 + tid] + s_part[32 + tid] + s_part[48 + tid];
        dst[idx * 16 + tid] = s;
    }
}

__global__ void __launch_bounds__(256)
k_mega_small(const float* __restrict__ cls_out, const float* __restrict__ wh_out,
             const float* __restrict__ kp_out,  const float* __restrict__ ae_out,
             const float* __restrict__ tan_out, const float* __restrict__ cls_mask,
             const float* __restrict__ wh_target, const float* __restrict__ wh_mask,
             const float* __restrict__ kp_mask, const float* __restrict__ ae_masks,
             const float* __restrict__ tan_normals,
             const int* __restrict__ centers, const int* __restrict__ kps,
             const int* __restrict__ tan_points, float* __restrict__ ws) {
    __shared__ float smem[256];
    int bid = blockIdx.x;
    if (bid < S_NBLK_INST) {
        inst_r10(bid, ae_out, ae_masks, centers, ws + S_INST, smem);
    } else if (bid < S_OFF_FOCAL) {
        wh_part(bid - S_OFF_WH, wh_out, wh_target, wh_mask, ws + S_WH, smem);
    } else if (bid < S_OFF_TAN) {
        focal_part(bid - S_OFF_FOCAL, cls_out, cls_mask, kp_out, kp_mask, ws + S_FOCAL, smem);
    } else if (bid < S_OFF_VAR) {
        tan_part(bid - S_OFF_TAN, tan_out, tan_normals, tan_points, ws + S_TAN, smem);
    } else {
        var_part(bid - S_OFF_VAR, ae_out, centers, kps, ws + S_VAR, smem);
    }
}

__global__ void __launch_bounds__(256)
k_final_small(const float* __restrict__ ws, float* __restrict__ out) {
    __shared__ float sbuf[4];
    int tid = threadIdx.x;
    float ae_v = 0.f;
    if (tid < 128) {
        int b = tid >> 5, n = tid & 31, grp = n >> 3, i = n & 7;
        const float* base = ws + S_INST + ((b * 4 + grp) * 32) * 16 + i * 2;
        float sum = 0.f, cnt = 0.f;
        #pragma unroll 8
        for (int seg = 0; seg < 32; ++seg) { sum += base[seg * 16]; cnt += base[seg * 16 + 1]; }
        ae_v = -sum / fmaxf(cnt, 1.0f) + ws[S_VAR + tid];
    }
    float ae_sum = block_reduce(ae_v, sbuf);

    float cls_sum = block_reduce(ws[S_FOCAL + tid * 2], sbuf);
    float cls_cnt = block_reduce(ws[S_FOCAL + tid * 2 + 1], sbuf);
    float kp_sum  = block_reduce(ws[S_FOCAL + 512 + tid * 2], sbuf);
    float kp_cnt  = block_reduce(ws[S_FOCAL + 512 + tid * 2 + 1], sbuf);
    float wh_sl   = block_reduce(ws[S_WH + tid * 2], sbuf);
    float wh_ms   = block_reduce(ws[S_WH + tid * 2 + 1], sbuf);
    float tan_sum = block_reduce(tid < 32 ? ws[S_TAN + tid] : 0.f, sbuf);

    if (tid == 0) {
        float l_cls = -cls_sum / fmaxf(cls_cnt, 1.0f);
        float l_kp  = -kp_sum  / fmaxf(kp_cnt,  1.0f);
        float l_wh  = 0.1f * wh_sl / (wh_ms + 1e-4f);
        float l_ae  = ae_sum / (float)(NN * BB);
        float l_tan = tan_sum / (float)(PP * BB);
        out[0] = l_cls + l_wh + l_kp + l_ae + l_tan;
    }
}

extern "C" void kernel_launch(void* const* d_in, const int* in_sizes, int n_in,
                              void* d_out, int out_size, void* d_ws, size_t ws_size,
                              hipStream_t stream) {
    const float* cls_out     = (const float*)d_in[0];
    const float* wh_out      = (const float*)d_in[1];
    const float* kp_out      = (const float*)d_in[2];
    const float* ae_out      = (const float*)d_in[3];
    const float* tan_out     = (const float*)d_in[4];
    const float* cls_mask    = (const float*)d_in[5];
    const float* wh_target   = (const float*)d_in[6];
    const float* wh_mask     = (const float*)d_in[7];
    const float* kp_mask     = (const float*)d_in[8];
    const float* ae_masks    = (const float*)d_in[9];
    const float* tan_normals = (const float*)d_in[10];
    const int* centers    = (const int*)d_in[12];
    const int* kps        = (const int*)d_in[13];
    const int* tan_points = (const int*)d_in[14];
    float* ws  = (float*)d_ws;
    float* out = (float*)d_out;

    if (ws_size >= (size_t)B_END * 4) {
        k_pre<<<1024, 256, 0, stream>>>(ae_out, ws);
        k_sweep<<<BGS_TOTAL, 256, 0, stream>>>(cls_out, wh_out, kp_out, ae_out, tan_out,
                                               cls_mask, wh_target, wh_mask, kp_mask,
                                               ae_masks, tan_normals, centers, kps,
                                               tan_points, ws);
        k_final_big<<<1, 256, 0, stream>>>(ws, out);
    } else {
        k_mega_small<<<S_NBLK_TOTAL, 256, 0, stream>>>(cls_out, wh_out, kp_out, ae_out,
                                                       tan_out, cls_mask, wh_target,
                                                       wh_mask, kp_mask, ae_masks,
                                                       tan_normals, centers, kps,
                                                       tan_points, ws);
        k_final_small<<<1, 256, 0, stream>>>(ws, out);
    }
}